// Round 11
// baseline (87.864 us; speedup 1.0000x reference)
//
#include <hip/hip_runtime.h>

#define IN_C 32
#define HW 64
#define Q_N 36

typedef float f32x4 __attribute__((ext_vector_type(4)));
typedef short s16x8 __attribute__((ext_vector_type(8)));
typedef short s16x4 __attribute__((ext_vector_type(4)));

// workspace layout (bytes)
#define WEXP_OFF 0          // [36 q][4 mt][16 pr][8 j] bf16 = 73728 B
#define ZW_OFF   73728      // 36864 B zeros (A-fragment pad, full q-stride replicated)
#define SCL_OFF  110592     // f32[36] signed scale * E
#define GX2_OFF  112640     // bf16 GAIN*x^2, [8][32][64][64] = 2097152 B

__device__ __forceinline__ unsigned short f2bf(float f) {
    union { float f; unsigned int u; } v; v.f = f;
    unsigned int t = v.u + 0x7FFFu + ((v.u >> 16) & 1u);   // RNE
    return (unsigned short)(t >> 16);
}

// exact-double constants, folded to float at compile time
#define A_D  0.8578
#define R_D  0.8985
#define C2_D (2.0 * A_D * R_D)                 // 1.5414666...
#define D_D  (1.0 + (A_D*R_D)*(A_D*R_D))
#define S_D  (A_D*A_D + R_D*R_D)
#define E_D  (S_D - D_D)                       // tr = 1 + E/den; sum_q sc = 0 kills the 1
#define B0_F ((float)(D_D - C2_D))
// den(phi) = D - C2*cos(phi) = B0 + u*(B1 + u*(B2 + ... )), u = phi^2  (Taylor, exact at u->0)
#define B1_F ((float)( C2_D / 2.0))
#define B2_F ((float)(-C2_D / 24.0))
#define B3_F ((float)( C2_D / 720.0))
#define B4_F ((float)(-C2_D / 40320.0))
#define B5_F ((float)( C2_D / 3628800.0))
#define B6_F ((float)(-C2_D / 479001600.0))
#define B7_F ((float)( C2_D / 87178291200.0))
#define GAIN_F 1.6666666666666667f             // MORR gain 10/6 (phases in radians now)

__global__ __launch_bounds__(512)
void morr_pre(const float* __restrict__ x,
              const float* __restrict__ weight,
              const float* __restrict__ mos,
              unsigned char* __restrict__ ws)
{
    const int tid = threadIdx.x;
    const int blk = blockIdx.x;
    if (blk < 512) {
        const int i = (blk * 512 + tid) * 4;
        float4 v = *(const float4*)(x + i);
        s16x4 o = {(short)f2bf(GAIN_F * v.x * v.x), (short)f2bf(GAIN_F * v.y * v.y),
                   (short)f2bf(GAIN_F * v.z * v.z), (short)f2bf(GAIN_F * v.w * v.w)};
        *(s16x4*)(ws + GX2_OFF + (size_t)i * 2) = o;
    } else {
        unsigned short* wexp = (unsigned short*)(ws + WEXP_OFF);
#pragma unroll
        for (int it = 0; it < 72; ++it) {
            const int idx = tid + 512 * it;
            const int q  = idx >> 9;
            const int mt = (idx >> 7) & 3;
            const int pr = (idx >> 3) & 15;
            const int j  = idx & 7;
            const int pk = mt * 16 + pr;
            const int p  = pk >> 3, k = pk & 7;
            wexp[idx] = f2bf(weight[p * 288 + q * 8 + ((k - j) & 7)]);
        }
        unsigned int* zw = (unsigned int*)(ws + ZW_OFF);
#pragma unroll
        for (int it = 0; it < 18; ++it) zw[tid + 512 * it] = 0;
        if (tid < Q_N)
            ((float*)(ws + SCL_OFF))[tid] =
                ((tid < 18) ? mos[tid] : -mos[tid - 18]) * (float)E_D;
    }
}

// block = half-row (32 px), 8 waves = 2 nt x 4 mt. grid = 8*64*2 = 1024 (4/CU).
__global__ __launch_bounds__(512, 8)
void morr_conv_kernel(const unsigned char* __restrict__ ws,
                      float* __restrict__ out)
{
    __shared__ __align__(16) unsigned short Aim[32 * 296];   // 18944 B

    const int tid = threadIdx.x;
    const int blk = blockIdx.x;
    const int b   = blk >> 7;
    const int rem = blk & 127;
    const int row = rem >> 1;
    const int w0  = (rem & 1) << 5;

    const unsigned short* gx2 = (const unsigned short*)(ws + GX2_OFF);

    // ---- stage im2col: thread (px=tid&31, g=tid>>5) owns channels 2g,2g+1 ----
    {
        const int px = tid & 31;
        const int g  = tid >> 5;
        unsigned short e[18];
#pragma unroll
        for (int cc = 0; cc < 2; ++cc) {
            const int c = 2 * g + cc;
            const unsigned short* xc = gx2 + ((b * IN_C + c) << 12);
#pragma unroll
            for (int ki = 0; ki < 3; ++ki) {
                const int gh = row + ki - 1;
                const bool rok = (unsigned)gh < 64u;
#pragma unroll
                for (int kj = 0; kj < 3; ++kj) {
                    const int gw = w0 + px + kj - 1;
                    unsigned short v = 0;
                    if (rok && (unsigned)gw < 64u) v = xc[(gh << 6) + gw];
                    e[cc * 9 + ki * 3 + kj] = v;
                }
            }
        }
        unsigned int* dst = (unsigned int*)((unsigned char*)Aim + px * 592 + g * 36);
#pragma unroll
        for (int i = 0; i < 9; ++i)
            dst[i] = (unsigned)e[2 * i] | ((unsigned)e[2 * i + 1] << 16);
    }
    __syncthreads();

    const int wv = tid >> 6;
    const int l  = tid & 63;
    const int ll = l & 15;
    const int lh = l >> 4;
    const int nt = wv & 1;           // px tile
    const int mt = wv >> 1;          // pk tile

    const unsigned short* bB = Aim + (nt * 16 + ll) * 296;
    // A: lanes l<16 real weights, l>=16 zero page; uniform q-stride 512 ushorts
    const unsigned short* aW = (l < 16)
        ? (const unsigned short*)(ws + WEXP_OFF) + (mt * 16 + ll) * 8
        : (const unsigned short*)(ws + ZW_OFF);
    const float* __restrict__ sp = (const float*)(ws + SCL_OFF);

    float acc[4] = {0.f, 0.f, 0.f, 0.f};
    const f32x4 cz = {0.f, 0.f, 0.f, 0.f};

#pragma unroll
    for (int qg = 0; qg < 9; ++qg) {
        f32x4 d0, d1, d2, d3;
        {
            const int q = qg * 4;
            s16x8 bf0 = *(const s16x8*)(bB + (q + 0) * 8);
            s16x8 a0  = *(const s16x8*)(aW + (q + 0) * 512);
            d0 = __builtin_amdgcn_mfma_f32_16x16x32_bf16(a0, bf0, cz, 0, 0, 0);
            s16x8 bf1 = *(const s16x8*)(bB + (q + 1) * 8);
            s16x8 a1  = *(const s16x8*)(aW + (q + 1) * 512);
            d1 = __builtin_amdgcn_mfma_f32_16x16x32_bf16(a1, bf1, cz, 0, 0, 0);
            s16x8 bf2 = *(const s16x8*)(bB + (q + 2) * 8);
            s16x8 a2  = *(const s16x8*)(aW + (q + 2) * 512);
            d2 = __builtin_amdgcn_mfma_f32_16x16x32_bf16(a2, bf2, cz, 0, 0, 0);
            s16x8 bf3 = *(const s16x8*)(bB + (q + 3) * 8);
            s16x8 a3  = *(const s16x8*)(aW + (q + 3) * 512);
            d3 = __builtin_amdgcn_mfma_f32_16x16x32_bf16(a3, bf3, cz, 0, 0, 0);
        }
        const float s0 = sp[qg * 4 + 0];
        const float s1 = sp[qg * 4 + 1];
        const float s2 = sp[qg * 4 + 2];
        const float s3 = sp[qg * 4 + 3];
#pragma unroll
        for (int r = 0; r < 4; ++r) {
            float den[4];
            float z[4] = {d0[r], d1[r], d2[r], d3[r]};
#pragma unroll
            for (int i = 0; i < 4; ++i) {
                const float u = z[i] * z[i];
                float p = fmaf(B7_F, u, B6_F);
                p = fmaf(p, u, B5_F);
                p = fmaf(p, u, B4_F);
                p = fmaf(p, u, B3_F);
                p = fmaf(p, u, B2_F);
                p = fmaf(p, u, B1_F);
                den[i] = fmaf(p, u, B0_F);
            }
            float dd01 = den[0] * den[1];
            float n01  = den[1] * s0;  n01 = fmaf(den[0], s1, n01);
            float dd23 = den[2] * den[3];
            float n23  = den[3] * s2;  n23 = fmaf(den[2], s3, n23);
            float dd = dd01 * dd23;
            float n  = n01 * dd23;     n = fmaf(n23, dd01, n);
            acc[r] = fmaf(n, __builtin_amdgcn_rcpf(dd), acc[r]);
        }
    }

    // ---- store: pk = mt*16 + lh*4 + r, col = w0 + nt*16 + ll ----
    const int col = w0 + nt * 16 + ll;
#pragma unroll
    for (int r = 0; r < 4; ++r) {
        const int pk = mt * 16 + lh * 4 + r;
        out[(b * 64 + pk) * (HW * HW) + row * HW + col] = acc[r];
    }
}

extern "C" void kernel_launch(void* const* d_in, const int* in_sizes, int n_in,
                              void* d_out, int out_size, void* d_ws, size_t ws_size,
                              hipStream_t stream) {
    const float* x      = (const float*)d_in[0];
    const float* weight = (const float*)d_in[1];
    const float* mos    = (const float*)d_in[2];
    float* out = (float*)d_out;
    unsigned char* ws = (unsigned char*)d_ws;

    hipLaunchKernelGGL(morr_pre, dim3(513), dim3(512), 0, stream, x, weight, mos, ws);
    // 8 images x 64 rows x 2 half-rows
    hipLaunchKernelGGL(morr_conv_kernel, dim3(1024), dim3(512), 0, stream, ws, out);
}

// Round 12
// 83.456 us; speedup vs baseline: 1.0528x; 1.0528x over previous
//
#include <hip/hip_runtime.h>

#define IN_C 32
#define HW 64
#define Q_N 36

typedef float f32x4 __attribute__((ext_vector_type(4)));
typedef short s16x8 __attribute__((ext_vector_type(8)));
typedef short s16x4 __attribute__((ext_vector_type(4)));

// workspace layout (bytes)
#define WEXP_OFF 0          // [36 q][4 mt][16 pr][8 j] bf16 = 73728 B
#define ZW_OFF   73728      // 512 B zeros (A-fragment K-padding lanes l>=16)
#define SCL_OFF  74240      // f32[36] signed scale * E
#define GX2_OFF  75776      // bf16 GI*x^2, [8][32][64][64] = 2097152 B

__device__ __forceinline__ unsigned short f2bf(float f) {
    union { float f; unsigned int u; } v; v.f = f;
    unsigned int t = v.u + 0x7FFFu + ((v.u >> 16) & 1u);   // RNE
    return (unsigned short)(t >> 16);
}

#define A_C 0.8578f
#define R_C 0.8985f
#define S_C (A_C*A_C + R_C*R_C)
#define D_C (1.f + (A_C*R_C)*(A_C*R_C))
#define C2_C (2.f*A_C*R_C)
#define E_C (S_C - D_C)
// MORR gain (10/6) folded with 1/(2*pi): v_cos takes revolutions
#define GI_C (1.6666666666666667f * 0.15915494309189535f)

__global__ __launch_bounds__(512)
void morr_pre(const float* __restrict__ x,
              const float* __restrict__ weight,
              const float* __restrict__ mos,
              unsigned char* __restrict__ ws)
{
    const int tid = threadIdx.x;
    const int blk = blockIdx.x;
    if (blk < 512) {
        const int i = (blk * 512 + tid) * 4;
        float4 v = *(const float4*)(x + i);
        s16x4 o = {(short)f2bf(GI_C * v.x * v.x), (short)f2bf(GI_C * v.y * v.y),
                   (short)f2bf(GI_C * v.z * v.z), (short)f2bf(GI_C * v.w * v.w)};
        *(s16x4*)(ws + GX2_OFF + (size_t)i * 2) = o;
    } else {
        unsigned short* wexp = (unsigned short*)(ws + WEXP_OFF);
#pragma unroll
        for (int it = 0; it < 72; ++it) {
            const int idx = tid + 512 * it;
            const int q  = idx >> 9;
            const int mt = (idx >> 7) & 3;
            const int pr = (idx >> 3) & 15;
            const int j  = idx & 7;
            const int pk = mt * 16 + pr;
            const int p  = pk >> 3, k = pk & 7;
            wexp[idx] = f2bf(weight[p * 288 + q * 8 + ((k - j) & 7)]);
        }
        if (tid < 128) ((float*)(ws + ZW_OFF))[tid] = 0.f;
        if (tid < Q_N)
            ((float*)(ws + SCL_OFF))[tid] =
                ((tid < 18) ? mos[tid] : -mos[tid - 18]) * E_C;
    }
}

// R9 shape: block = full row (64 px), 8 waves = 4 nt x 2 m0-pairs; grid 512.
__global__ __launch_bounds__(512, 4)
void morr_conv_kernel(const unsigned char* __restrict__ ws,
                      float* __restrict__ out)
{
    __shared__ __align__(16) unsigned short Aim[64 * 296];   // 37888 B

    const int tid = threadIdx.x;
    const int blk = blockIdx.x;
    const int b   = blk >> 6;
    const int row = blk & 63;

    const unsigned short* gx2 = (const unsigned short*)(ws + GX2_OFF);

    // ---- stage im2col: thread (px=tid&63, g=tid>>6) owns channels 4g..4g+3 ----
    {
        const int px = tid & 63;
        const int g  = tid >> 6;
        unsigned short buf[36];
#pragma unroll
        for (int cc = 0; cc < 4; ++cc) {
            const int c = g * 4 + cc;
            const unsigned short* xc = gx2 + ((b * IN_C + c) << 12);
#pragma unroll
            for (int ki = 0; ki < 3; ++ki) {
                const int gh = row + ki - 1;
                const bool rok = (unsigned)gh < 64u;
#pragma unroll
                for (int kj = 0; kj < 3; ++kj) {
                    const int gw = px + kj - 1;
                    unsigned short v = 0;
                    if (rok && (unsigned)gw < 64u) v = xc[(gh << 6) + gw];
                    buf[cc * 9 + ki * 3 + kj] = v;
                }
            }
        }
        unsigned short* dst = Aim + px * 296 + g * 36;
#pragma unroll
        for (int i = 0; i < 9; ++i) {
            s16x4 v = {(short)buf[i*4], (short)buf[i*4+1],
                       (short)buf[i*4+2], (short)buf[i*4+3]};
            *(s16x4*)(dst + i * 4) = v;
        }
    }
    __syncthreads();

    const int wv = tid >> 6;         // wave 0..7
    const int l  = tid & 63;
    const int ll = l & 15;
    const int lh = l >> 4;
    const int nt = wv & 3;           // px tile (N)
    const int m0 = (wv >> 2) * 2;    // first of 2 pk tiles (M)

    const unsigned short* bB = Aim + (nt * 16 + ll) * 296;
    const unsigned short* aW;
    int qs;
    if (l < 16) { aW = (const unsigned short*)(ws + WEXP_OFF) + (m0 * 16 + ll) * 8; qs = 512; }
    else        { aW = (const unsigned short*)(ws + ZW_OFF);                        qs = 0;   }
    const float* __restrict__ sp = (const float*)(ws + SCL_OFF);

    float acc[8];
#pragma unroll
    for (int i = 0; i < 8; ++i) acc[i] = 0.f;

    const f32x4 cz = {0.f, 0.f, 0.f, 0.f};

    // process q in pairs; per pair share one rcp per output element:
    //   s0/den0 + s1/den1 = (s0*den1 + s1*den0) * rcp(den0*den1)
#pragma unroll
    for (int qg = 0; qg < 18; ++qg) {
        const int q = qg * 2;
        s16x8 bf0 = *(const s16x8*)(bB + q * 8);
        s16x8 a00 = *(const s16x8*)(aW + q * qs);
        s16x8 a01 = *(const s16x8*)(aW + q * qs + 128);
        f32x4 d00 = __builtin_amdgcn_mfma_f32_16x16x32_bf16(a00, bf0, cz, 0, 0, 0);
        f32x4 d01 = __builtin_amdgcn_mfma_f32_16x16x32_bf16(a01, bf0, cz, 0, 0, 0);
        s16x8 bf1 = *(const s16x8*)(bB + (q + 1) * 8);
        s16x8 a10 = *(const s16x8*)(aW + (q + 1) * qs);
        s16x8 a11 = *(const s16x8*)(aW + (q + 1) * qs + 128);
        f32x4 d10 = __builtin_amdgcn_mfma_f32_16x16x32_bf16(a10, bf1, cz, 0, 0, 0);
        f32x4 d11 = __builtin_amdgcn_mfma_f32_16x16x32_bf16(a11, bf1, cz, 0, 0, 0);
        const float s0 = sp[q];
        const float s1 = sp[q + 1];
#pragma unroll
        for (int r = 0; r < 4; ++r) {
            // tile 0 (pk tile m0)
            {
                float den0 = fmaf(-C2_C, __builtin_amdgcn_cosf(d00[r]), D_C);
                float den1 = fmaf(-C2_C, __builtin_amdgcn_cosf(d10[r]), D_C);
                float num  = den1 * s0;
                num = fmaf(den0, s1, num);
                acc[r] = fmaf(num, __builtin_amdgcn_rcpf(den0 * den1), acc[r]);
            }
            // tile 1 (pk tile m0+1)
            {
                float den0 = fmaf(-C2_C, __builtin_amdgcn_cosf(d01[r]), D_C);
                float den1 = fmaf(-C2_C, __builtin_amdgcn_cosf(d11[r]), D_C);
                float num  = den1 * s0;
                num = fmaf(den0, s1, num);
                acc[4 + r] = fmaf(num, __builtin_amdgcn_rcpf(den0 * den1), acc[4 + r]);
            }
        }
    }

    // ---- store: D layout col=l&15 (px), row=(l>>4)*4+r (pk within tile) ----
    const int col = nt * 16 + ll;
#pragma unroll
    for (int t = 0; t < 2; ++t) {
#pragma unroll
        for (int r = 0; r < 4; ++r) {
            const int pk = (m0 + t) * 16 + lh * 4 + r;
            out[(b * 64 + pk) * (HW * HW) + row * HW + col] = acc[t * 4 + r];
        }
    }
}

extern "C" void kernel_launch(void* const* d_in, const int* in_sizes, int n_in,
                              void* d_out, int out_size, void* d_ws, size_t ws_size,
                              hipStream_t stream) {
    const float* x      = (const float*)d_in[0];
    const float* weight = (const float*)d_in[1];
    const float* mos    = (const float*)d_in[2];
    float* out = (float*)d_out;
    unsigned char* ws = (unsigned char*)d_ws;

    hipLaunchKernelGGL(morr_pre, dim3(513), dim3(512), 0, stream, x, weight, mos, ws);
    hipLaunchKernelGGL(morr_conv_kernel, dim3(512), dim3(512), 0, stream, ws, out);
}